// Round 4
// baseline (198.955 us; speedup 1.0000x reference)
//
#include <hip/hip_runtime.h>
#include <hip/hip_bf16.h>

typedef unsigned long long u64;
typedef unsigned int u32;

#define NB   64
#define NPOS 1024
#define NOUT 25
#define NCLS 20
#define WROW 32            // f64 weights per channel row, padded to 256 B

// ---- workspace layout (bytes) ----
#define OFF_W64   0          // double wpad[512*32] = 131072
#define OFF_B64   131072     // double b64[25]      = 200 (pad to 131328)
#define OFF_ORDER 131328     // int    order[64*1024]   = 262144
#define OFF_SBOX  393472     // float4 sbox[64*1024]    = 1048576
#define OFF_SCLS  1442048    // int    scls[64*1024]    = 262144
#define OFF_VALID 1704192    // u64    validW[64*16]    = 8192
#define OFF_MASK  1712384    // u64    masks[64*1024*16]= 8388608 -> end 10100992

// ---------------- kernel 0: weights -> f64, layout [c][32] (pad 0) -----------
__global__ __launch_bounds__(256) void k_cvt(const float* __restrict__ w,
                                             const float* __restrict__ bias,
                                             double* __restrict__ wpad,
                                             double* __restrict__ b64)
{
    int idx = blockIdx.x * 256 + threadIdx.x;
    if (idx < 512 * WROW) {
        int c = idx >> 5, o = idx & 31;
        wpad[idx] = (o < NOUT) ? (double)w[o * 512 + c] : 0.0;
    }
    if (idx < NOUT) b64[idx] = (double)bias[idx];
}

// ---------------- kernel 1: f64 GEMV, scalar-cache weights, split-K=2 --------
// block 512 = 256 positions x 2 K-slices; grid (4,64) = 256 blocks (1/CU),
// 8 waves/CU = 2/SIMD. Weights read via wave-uniform address (readfirstlane)
// -> s_load through the scalar cache: zero LDS/VALU cost in the main loop.
__global__ __launch_bounds__(512, 2) void k_main(const float* __restrict__ feat,
                                                 const double* __restrict__ wpad_g,
                                                 const double* __restrict__ b64,
                                                 float* __restrict__ boxes_out,
                                                 float* __restrict__ scores_out,
                                                 float* __restrict__ cls_out)
{
    __shared__ __align__(16) double red[256 * NOUT];   // 51200 B, end-only
    const int b   = blockIdx.y;
    const int tid = threadIdx.x;
    const int pl  = tid & 255;                          // position within block
    const int su  = __builtin_amdgcn_readfirstlane(tid >> 8);  // slice 0/1, uniform
    const int cbase = su * 256;
    const int n   = blockIdx.x * 256 + pl;

    const float* __restrict__ fp = feat + (size_t)b * 512 * NPOS
                                        + (size_t)cbase * NPOS + n;

    double acc[NOUT];
#pragma unroll
    for (int o = 0; o < NOUT; ++o) acc[o] = 0.0;

#define CH(V, CC) do {                                                        \
    const double* __restrict__ wr = wpad_g + ((size_t)(CC) << 5);             \
    double v = (double)(V);                                                   \
    _Pragma("unroll")                                                         \
    for (int o = 0; o < NOUT; ++o) acc[o] = fma(v, wr[o], acc[o]);            \
} while (0)

    // 256 channels in groups of 8; 3 buffers -> loads issued 2 groups (1600cy) ahead
    float fa[8], fb[8], fc[8];
#pragma unroll
    for (int u = 0; u < 8; ++u) fa[u] = fp[(size_t)u * NPOS];
#pragma unroll
    for (int u = 0; u < 8; ++u) fb[u] = fp[(size_t)(8 + u) * NPOS];

#pragma unroll 1
    for (int g = 0; g < 32; ++g) {
        int tnext = (g + 2 < 32) ? (g + 2) * 8 : 0;
#pragma unroll
        for (int u = 0; u < 8; ++u) fc[u] = fp[(size_t)(tnext + u) * NPOS];
        int c0 = cbase + g * 8;
        CH(fa[0], c0 + 0); CH(fa[1], c0 + 1); CH(fa[2], c0 + 2); CH(fa[3], c0 + 3);
        CH(fa[4], c0 + 4); CH(fa[5], c0 + 5); CH(fa[6], c0 + 6); CH(fa[7], c0 + 7);
#pragma unroll
        for (int u = 0; u < 8; ++u) { fa[u] = fb[u]; fb[u] = fc[u]; }
    }
#undef CH

    // -------- deterministic reduce: acc = slice0 + slice1 --------
    __syncthreads();
    if (su == 1) {
#pragma unroll
        for (int o = 0; o < NOUT; ++o) red[pl * NOUT + o] = acc[o];
    }
    __syncthreads();
    if (su == 0) {
#pragma unroll
        for (int o = 0; o < NOUT; ++o) acc[o] += red[pl * NOUT + o];

        // ---------------- epilogue (f64) ----------------
        double p[NOUT];
#pragma unroll
        for (int o = 0; o < NOUT; ++o) p[o] = acc[o] + b64[o];

        double conf = 1.0 / (1.0 + exp(-p[0]));
        double m = p[1];
#pragma unroll
        for (int i = 2; i <= NCLS; ++i) m = fmax(m, p[i]);
        double e[NCLS];
        double ssum = 0.0;
#pragma unroll
        for (int i = 0; i < NCLS; ++i) { e[i] = exp(p[1 + i] - m); ssum += e[i]; }
        double best = -1.0; int ci = 0;
#pragma unroll
        for (int i = 0; i < NCLS; ++i) {
            double si = conf * (e[i] / ssum);
            if (si > best) { best = si; ci = i; }
        }

        int gx = n & 31, gy = n >> 5;
        double sx = 1.0 / (1.0 + exp(-p[21]));
        double sy = 1.0 / (1.0 + exp(-p[22]));
        double cx = (sx + (double)gx) * 32.0;
        double cy = (sy + (double)gy) * 32.0;
        double bw = exp(p[23]), bh = exp(p[24]);
        double x1 = (cx - bw * 0.5) * (1.0 / 1024.0);
        double y1 = (cy - bh * 0.5) * (1.0 / 1024.0);
        double x2 = (cx + bw * 0.5) * (1.0 / 1024.0);
        double y2 = (cy + bh * 0.5) * (1.0 / 1024.0);
        x1 = fmin(fmax(x1, 0.0), 1.0); y1 = fmin(fmax(y1, 0.0), 1.0);
        x2 = fmin(fmax(x2, 0.0), 1.0); y2 = fmin(fmax(y2, 0.0), 1.0);

        int gi = b * NPOS + n;
        ((float4*)boxes_out)[gi] = make_float4((float)x1, (float)y1, (float)x2, (float)y2);
        scores_out[gi] = (float)best;
        cls_out[gi]    = (float)ci;
    }
}

// ---------------- kernel 2: per-batch bitonic sort (desc score, stable) -------
__global__ __launch_bounds__(256) void k_sort(const float* __restrict__ scores,
                                              const float* __restrict__ boxes,
                                              const float* __restrict__ cls,
                                              int* __restrict__ order,
                                              float4* __restrict__ sbox,
                                              int* __restrict__ scls,
                                              u64* __restrict__ validW)
{
    __shared__ u64 key[NPOS];
    __shared__ u64 vw[16];
    int b = blockIdx.x, tid = threadIdx.x;

    for (int ppos = tid; ppos < NPOS; ppos += 256) {
        u32 bits = __float_as_uint(scores[b * NPOS + ppos]);
        u32 d = ~(bits | 0x80000000u);   // descending-monotone key (scores >= 0)
        key[ppos] = ((u64)d << 32) | (u32)ppos;
    }
    if (tid < 16) vw[tid] = 0ull;
    __syncthreads();

    for (int k = 2; k <= NPOS; k <<= 1) {
        for (int j = k >> 1; j > 0; j >>= 1) {
            for (int idx = tid; idx < NPOS; idx += 256) {
                int l = idx ^ j;
                if (l > idx) {
                    u64 a = key[idx], c = key[l];
                    bool up = ((idx & k) == 0);
                    if ((a > c) == up) { key[idx] = c; key[l] = a; }
                }
            }
            __syncthreads();
        }
    }

    for (int ppos = tid; ppos < NPOS; ppos += 256) {
        u64 kk = key[ppos];
        int idx = (int)(kk & 0xffffffffu);
        order[b * NPOS + ppos] = idx;
        sbox [b * NPOS + ppos] = ((const float4*)boxes)[b * NPOS + idx];
        scls [b * NPOS + ppos] = (int)cls[b * NPOS + idx];
        u32 sb = (~(u32)(kk >> 32)) & 0x7fffffffu;
        float sc = __uint_as_float(sb);
        if (sc > 0.01f) atomicOr(&vw[ppos >> 6], 1ull << (ppos & 63));
    }
    __syncthreads();
    if (tid < 16) validW[b * 16 + tid] = vw[tid];
}

// ---------------- kernel 3: suppression bitmask build (upper triangle) --------
__global__ __launch_bounds__(256) void k_mask(const float4* __restrict__ sbox,
                                              const int* __restrict__ scls,
                                              u64* __restrict__ masks)
{
    __shared__ float4 boxl[NPOS];
    __shared__ float  arl[NPOS];
    __shared__ int    cll[NPOS];
    int b = blockIdx.y, rb = blockIdx.x, tid = threadIdx.x;

    for (int ppos = tid; ppos < NPOS; ppos += 256) {
        float4 bb = sbox[b * NPOS + ppos];
        boxl[ppos] = bb;
        arl[ppos] = (bb.z - bb.x) * (bb.w - bb.y);
        cll[ppos] = scls[b * NPOS + ppos];
    }
    __syncthreads();

    int i = rb * 64 + (tid >> 2);
    int wbase = tid & 3;
    float4 bi = boxl[i];
    float ai = arl[i];
    int ci_ = cll[i];
    u64* mrow = masks + ((size_t)(b * NPOS + i) << 4);

#pragma unroll
    for (int s = 0; s < 4; ++s) {
        int w = wbase + 4 * s;
        u64 bits = 0ull;
        if (w >= rb) {
            for (int t = 0; t < 64; ++t) {
                int jj = (t + 2 * wbase) & 63;
                int j = w * 64 + jj;
                float4 bj = boxl[j];
                float xx1 = fmaxf(bi.x, bj.x), yy1 = fmaxf(bi.y, bj.y);
                float xx2 = fminf(bi.z, bj.z), yy2 = fminf(bi.w, bj.w);
                float ww = fmaxf(1e-28f, xx2 - xx1);
                float hh = fmaxf(1e-28f, yy2 - yy1);
                float inter = ww * hh;
                float uni = ai + arl[j] - inter;
                bool sup = (cll[j] == ci_) && (uni > 0.0f) &&
                           (inter > 0.5f * uni) && (j > i);
                bits |= ((u64)sup) << jj;
            }
        }
        mrow[w] = bits;
    }
}

// ---------------- kernel 4: sequential suppression scan + scatter keep --------
__global__ __launch_bounds__(64) void k_scan(const u64* __restrict__ validW,
                                             const u64* __restrict__ masks,
                                             const int* __restrict__ order,
                                             float* __restrict__ keep_out)
{
    int b = blockIdx.x, lane = threadIdx.x;
    u64 keep = (lane < 16) ? validW[b * 16 + lane] : 0ull;
    const u64* M = masks + (size_t)b * NPOS * 16;
    int myrow = lane >> 4;
    int myw = lane & 15;

    u64 buf[8];
#pragma unroll
    for (int d = 0; d < 8; ++d)
        buf[d] = M[(d * 4 + myrow) * 16 + myw];

    for (int g0 = 0; g0 < 256; g0 += 8) {
#pragma unroll
        for (int d = 0; d < 8; ++d) {
            int g = g0 + d;
            u64 cur = buf[d];
            int gp = g + 8;
            buf[d] = (gp < 256) ? M[(gp * 4 + myrow) * 16 + myw] : 0ull;
            if (__any(cur != 0ull)) {
#pragma unroll
                for (int r = 0; r < 4; ++r) {
                    int i = g * 4 + r;
                    u64 kw = __shfl(keep, i >> 6);
                    if ((kw >> (i & 63)) & 1ull) {
                        u64 mm = __shfl(cur, r * 16 + myw);
                        if (lane < 16) keep &= ~mm;
                    }
                }
            }
        }
    }

#pragma unroll
    for (int t = 0; t < 16; ++t) {
        int ppos = t * 64 + lane;
        u64 kw = __shfl(keep, t);
        float v = ((kw >> lane) & 1ull) ? 1.0f : 0.0f;
        keep_out[b * NPOS + order[b * NPOS + ppos]] = v;
    }
}

// ------------------------------------------------------------------------------
extern "C" void kernel_launch(void* const* d_in, const int* in_sizes, int n_in,
                              void* d_out, int out_size, void* d_ws, size_t ws_size,
                              hipStream_t stream)
{
    const float* feat = (const float*)d_in[0];
    const float* w    = (const float*)d_in[1];
    const float* bias = (const float*)d_in[2];

    float* out = (float*)d_out;
    float* boxes_out  = out;
    float* scores_out = out + NB * NPOS * 4;
    float* cls_out    = out + NB * NPOS * 5;
    float* keep_out   = out + NB * NPOS * 6;

    char* ws = (char*)d_ws;
    double* wpad  = (double*)(ws + OFF_W64);
    double* b64   = (double*)(ws + OFF_B64);
    int*    order = (int*)   (ws + OFF_ORDER);
    float4* sbox  = (float4*)(ws + OFF_SBOX);
    int*    scls  = (int*)   (ws + OFF_SCLS);
    u64*    validW= (u64*)   (ws + OFF_VALID);
    u64*    masks = (u64*)   (ws + OFF_MASK);

    hipLaunchKernelGGL(k_cvt,  dim3(64),     dim3(256), 0, stream, w, bias, wpad, b64);
    hipLaunchKernelGGL(k_main, dim3(4, 64),  dim3(512), 0, stream, feat, wpad, b64,
                       boxes_out, scores_out, cls_out);
    hipLaunchKernelGGL(k_sort, dim3(64),     dim3(256), 0, stream, scores_out,
                       boxes_out, cls_out, order, sbox, scls, validW);
    hipLaunchKernelGGL(k_mask, dim3(16, 64), dim3(256), 0, stream, sbox, scls, masks);
    hipLaunchKernelGGL(k_scan, dim3(64),     dim3(64),  0, stream, validW, masks,
                       order, keep_out);
}

// Round 5
// 161.847 us; speedup vs baseline: 1.2293x; 1.2293x over previous
//
#include <hip/hip_runtime.h>
#include <hip/hip_bf16.h>

typedef unsigned long long u64;
typedef unsigned int u32;

#define NB   64
#define NPOS 1024
#define NOUT 25
#define NCLS 20
#define WROW 32            // f64 weights per channel row, padded to 256 B

// ---- workspace layout (bytes) ----
#define OFF_W64   0          // double wpad[512*32] = 131072
#define OFF_B64   131072     // double b64[25]      = 200 (pad to 131328)
#define OFF_ORDER 131328     // int    order[64*1024]   = 262144
#define OFF_SBOX  393472     // float4 sbox[64*1024]    = 1048576
#define OFF_SCLS  1442048    // int    scls[64*1024]    = 262144
#define OFF_VALID 1704192    // u64    validW[64*16]    = 8192
#define OFF_MASK  1712384    // u64    masksT[64][16][1024] = 8388608 -> end 10100992

// ---------------- kernel 0: weights -> f64, layout [c][32] (pad 0) -----------
__global__ __launch_bounds__(256) void k_cvt(const float* __restrict__ w,
                                             const float* __restrict__ bias,
                                             double* __restrict__ wpad,
                                             double* __restrict__ b64)
{
    int idx = blockIdx.x * 256 + threadIdx.x;
    if (idx < 512 * WROW) {
        int c = idx >> 5, o = idx & 31;
        wpad[idx] = (o < NOUT) ? (double)w[o * 512 + c] : 0.0;
    }
    if (idx < NOUT) b64[idx] = (double)bias[idx];
}

// ---------------- f64 epilogue: sigmoid/softmax/argmax + box decode ----------
__device__ __forceinline__ void epilogue(const double* __restrict__ acc,
                                         const double* __restrict__ b64,
                                         int n, int gi,
                                         float* __restrict__ boxes_out,
                                         float* __restrict__ scores_out,
                                         float* __restrict__ cls_out)
{
    double p[NOUT];
#pragma unroll
    for (int o = 0; o < NOUT; ++o) p[o] = acc[o] + b64[o];

    double conf = 1.0 / (1.0 + exp(-p[0]));
    // argmax over logits (== argmax of conf*softmax), first-max semantics
    double m = p[1]; int ci = 0;
#pragma unroll
    for (int i = 2; i <= NCLS; ++i) {
        if (p[i] > m) { m = p[i]; ci = i - 1; }
    }
    double ssum = 0.0;
#pragma unroll
    for (int i = 0; i < NCLS; ++i) ssum += exp(p[1 + i] - m);
    double best = conf / ssum;      // == conf * e_top/ssum with e_top = exp(0)

    int gx = n & 31, gy = n >> 5;
    double sx = 1.0 / (1.0 + exp(-p[21]));
    double sy = 1.0 / (1.0 + exp(-p[22]));
    double cx = (sx + (double)gx) * 32.0;
    double cy = (sy + (double)gy) * 32.0;
    double bw = exp(p[23]), bh = exp(p[24]);
    double x1 = (cx - bw * 0.5) * (1.0 / 1024.0);
    double y1 = (cy - bh * 0.5) * (1.0 / 1024.0);
    double x2 = (cx + bw * 0.5) * (1.0 / 1024.0);
    double y2 = (cy + bh * 0.5) * (1.0 / 1024.0);
    x1 = fmin(fmax(x1, 0.0), 1.0); y1 = fmin(fmax(y1, 0.0), 1.0);
    x2 = fmin(fmax(x2, 0.0), 1.0); y2 = fmin(fmax(y2, 0.0), 1.0);

    ((float4*)boxes_out)[gi] = make_float4((float)x1, (float)y1, (float)x2, (float)y2);
    scores_out[gi] = (float)best;
    cls_out[gi]    = (float)ci;
}

// ---------------- kernel 1: f64 GEMV, scalar weights, P=2 x splitK=4 ---------
// block 256 = 4 waves (one per K-slice of 128 ch); each lane: 2 positions
// (n0, n0+64). Per channel: 50 f64 FMA (200cy) covers s_load latency.
// grid (8,64) = 512 blocks -> 2 blocks/CU -> 2 waves/SIMD (VGPR<=128).
__global__ __launch_bounds__(256, 2) void k_main(const float* __restrict__ feat,
                                                 const double* __restrict__ wpad_g,
                                                 const double* __restrict__ b64,
                                                 float* __restrict__ boxes_out,
                                                 float* __restrict__ scores_out,
                                                 float* __restrict__ cls_out)
{
    __shared__ __align__(16) double red[2][128 * NOUT];   // 51200 B
    const int b    = blockIdx.y;
    const int tid  = threadIdx.x;
    const int lane = tid & 63;
    const int wv   = __builtin_amdgcn_readfirstlane(tid >> 6);   // K-slice 0..3
    const int cbase = wv * 128;
    const int n0   = blockIdx.x * 128 + lane;    // positions n0 and n0+64

    const float* __restrict__ fp = feat + (size_t)b * 512 * NPOS
                                        + (size_t)cbase * NPOS + n0;

    double acc0[NOUT], acc1[NOUT];
#pragma unroll
    for (int o = 0; o < NOUT; ++o) { acc0[o] = 0.0; acc1[o] = 0.0; }

    // depth-4 channel prefetch (2 feat values per channel)
    float a0[4], a1[4];
#pragma unroll
    for (int u = 0; u < 4; ++u) {
        a0[u] = fp[(size_t)u * NPOS];
        a1[u] = fp[(size_t)u * NPOS + 64];
    }
#pragma unroll 1
    for (int c0 = 0; c0 < 128; c0 += 4) {
        float n0f[4], n1f[4];
        int nc = (c0 + 4 < 128) ? c0 + 4 : 0;
#pragma unroll
        for (int u = 0; u < 4; ++u) {
            n0f[u] = fp[(size_t)(nc + u) * NPOS];
            n1f[u] = fp[(size_t)(nc + u) * NPOS + 64];
        }
#pragma unroll
        for (int u = 0; u < 4; ++u) {
            const double* __restrict__ wr = wpad_g + ((size_t)(cbase + c0 + u) << 5);
            double vA = (double)a0[u], vB = (double)a1[u];
#pragma unroll
            for (int o = 0; o < NOUT; ++o) {
                double wo = wr[o];
                acc0[o] = fma(vA, wo, acc0[o]);
                acc1[o] = fma(vB, wo, acc1[o]);
            }
        }
#pragma unroll
        for (int u = 0; u < 4; ++u) { a0[u] = n0f[u]; a1[u] = n1f[u]; }
    }

    // ---- deterministic reduce: (w0+w2) + (w1+w3) ----
    __syncthreads();
    if (wv >= 2) {
        double* dst = &red[wv - 2][0];
#pragma unroll
        for (int o = 0; o < NOUT; ++o) {
            dst[lane * NOUT + o]        = acc0[o];
            dst[(lane + 64) * NOUT + o] = acc1[o];
        }
    }
    __syncthreads();
    if (wv < 2) {
        const double* src = &red[wv][0];
#pragma unroll
        for (int o = 0; o < NOUT; ++o) {
            acc0[o] += src[lane * NOUT + o];
            acc1[o] += src[(lane + 64) * NOUT + o];
        }
    }
    __syncthreads();
    if (wv == 1) {
#pragma unroll
        for (int o = 0; o < NOUT; ++o) {
            red[0][lane * NOUT + o]        = acc0[o];
            red[0][(lane + 64) * NOUT + o] = acc1[o];
        }
    }
    __syncthreads();
    if (wv == 0) {
#pragma unroll
        for (int o = 0; o < NOUT; ++o) {
            acc0[o] += red[0][lane * NOUT + o];
            acc1[o] += red[0][(lane + 64) * NOUT + o];
        }
        int nA = n0, nB = n0 + 64;
        epilogue(acc0, b64, nA, b * NPOS + nA, boxes_out, scores_out, cls_out);
        epilogue(acc1, b64, nB, b * NPOS + nB, boxes_out, scores_out, cls_out);
    }
}

// ---------------- kernel 2: per-batch bitonic sort (desc score, stable) -------
__global__ __launch_bounds__(256) void k_sort(const float* __restrict__ scores,
                                              const float* __restrict__ boxes,
                                              const float* __restrict__ cls,
                                              int* __restrict__ order,
                                              float4* __restrict__ sbox,
                                              int* __restrict__ scls,
                                              u64* __restrict__ validW)
{
    __shared__ u64 key[NPOS];
    __shared__ u64 vw[16];
    int b = blockIdx.x, tid = threadIdx.x;

    for (int ppos = tid; ppos < NPOS; ppos += 256) {
        u32 bits = __float_as_uint(scores[b * NPOS + ppos]);
        u32 d = ~(bits | 0x80000000u);   // descending-monotone key (scores >= 0)
        key[ppos] = ((u64)d << 32) | (u32)ppos;
    }
    if (tid < 16) vw[tid] = 0ull;
    __syncthreads();

    for (int k = 2; k <= NPOS; k <<= 1) {
        for (int j = k >> 1; j > 0; j >>= 1) {
            for (int idx = tid; idx < NPOS; idx += 256) {
                int l = idx ^ j;
                if (l > idx) {
                    u64 a = key[idx], c = key[l];
                    bool up = ((idx & k) == 0);
                    if ((a > c) == up) { key[idx] = c; key[l] = a; }
                }
            }
            __syncthreads();
        }
    }

    for (int ppos = tid; ppos < NPOS; ppos += 256) {
        u64 kk = key[ppos];
        int idx = (int)(kk & 0xffffffffu);
        order[b * NPOS + ppos] = idx;
        sbox [b * NPOS + ppos] = ((const float4*)boxes)[b * NPOS + idx];
        scls [b * NPOS + ppos] = (int)cls[b * NPOS + idx];
        u32 sb = (~(u32)(kk >> 32)) & 0x7fffffffu;
        float sc = __uint_as_float(sb);
        if (sc > 0.01f) atomicOr(&vw[ppos >> 6], 1ull << (ppos & 63));
    }
    __syncthreads();
    if (tid < 16) validW[b * 16 + tid] = vw[tid];
}

// ---------------- kernel 3: suppression mask, ballot style -------------------
// grid (64, 64): blockIdx.x = w*4 + chunk (word w, 256-row i-chunk), 64 thr.
// Lane owns column j = w*64+lane (regs); serial i reads are wave-uniform LDS
// broadcasts; __ballot(sup) builds the word. masksT layout: [b][w][row].
__global__ __launch_bounds__(64) void k_mask(const float4* __restrict__ sbox,
                                             const int* __restrict__ scls,
                                             u64* __restrict__ masksT)
{
    __shared__ float4 boxl[256];
    __shared__ float2 acl[256];
    const int wc  = blockIdx.x;
    const int w   = wc >> 2, chunk = wc & 3;
    const int b   = blockIdx.y;
    const int lane = threadIdx.x;
    const int i0   = chunk * 256;
    const int imax = (w + 1) * 64;            // rows that can suppress into word w
    u64* __restrict__ mcol = masksT + (((size_t)b * 16 + w) << 10);

    const int jg = w * 64 + lane;
    float4 bj = sbox[b * NPOS + jg];
    float  aj = (bj.z - bj.x) * (bj.w - bj.y);
    int    cj = scls[b * NPOS + jg];

    int iend = imax - i0;                     // rows in this chunk needing compute
    if (iend > 256) iend = 256;

    if (iend > 0) {
        for (int i = lane; i < iend; i += 64) {
            float4 bb = sbox[b * NPOS + i0 + i];
            boxl[i] = bb;
            acl[i]  = make_float2((bb.z - bb.x) * (bb.w - bb.y),
                                  __int_as_float(scls[b * NPOS + i0 + i]));
        }
    }
    __syncthreads();

#pragma unroll 1
    for (int t = 0; t < 256; t += 64) {       // 64-row tiles
        u64 myword = 0ull;
        if (t < iend) {
#pragma unroll 1
            for (int s = 0; s < 64; s += 8) {
                u64 bits[8];
#pragma unroll
                for (int u = 0; u < 8; ++u) {
                    int i = t + s + u;
                    float4 bi = boxl[i];      // wave-uniform broadcast
                    float2 ac = acl[i];
                    float xx1 = fmaxf(bi.x, bj.x), yy1 = fmaxf(bi.y, bj.y);
                    float xx2 = fminf(bi.z, bj.z), yy2 = fminf(bi.w, bj.w);
                    float ww = fmaxf(1e-28f, xx2 - xx1);
                    float hh = fmaxf(1e-28f, yy2 - yy1);
                    float inter = ww * hh;
                    float uni = ac.x + aj - inter;
                    bool sup = (__float_as_int(ac.y) == cj) && (uni > 0.0f) &&
                               (inter > 0.5f * uni) && (jg > i0 + i) && (i < iend);
                    bits[u] = __ballot(sup);
                }
#pragma unroll
                for (int u = 0; u < 8; ++u)
                    myword = (lane == s + u) ? bits[u] : myword;
            }
        }
        mcol[i0 + t + lane] = myword;         // coalesced (row-major in word)
    }
}

// ---------------- kernel 4: sequential suppression scan + scatter keep --------
__global__ __launch_bounds__(64) void k_scan(const u64* __restrict__ validW,
                                             const u64* __restrict__ masksT,
                                             const int* __restrict__ order,
                                             float* __restrict__ keep_out)
{
    int b = blockIdx.x, lane = threadIdx.x;
    u64 keep = (lane < 16) ? validW[b * 16 + lane] : 0ull;
    const u64* M = masksT + ((size_t)b << 14);    // [16 words][1024 rows]
    int myrow = lane >> 4;
    int myw = lane & 15;

    u64 buf[8];
#pragma unroll
    for (int d = 0; d < 8; ++d)
        buf[d] = M[((size_t)myw << 10) + (d * 4 + myrow)];

    for (int g0 = 0; g0 < 256; g0 += 8) {
#pragma unroll
        for (int d = 0; d < 8; ++d) {
            int g = g0 + d;
            u64 cur = buf[d];
            int gp = g + 8;
            buf[d] = (gp < 256) ? M[((size_t)myw << 10) + (gp * 4 + myrow)] : 0ull;
            if (__any(cur != 0ull)) {
#pragma unroll
                for (int r = 0; r < 4; ++r) {
                    int i = g * 4 + r;
                    u64 kw = __shfl(keep, i >> 6);
                    if ((kw >> (i & 63)) & 1ull) {
                        u64 mm = __shfl(cur, r * 16 + myw);
                        if (lane < 16) keep &= ~mm;
                    }
                }
            }
        }
    }

#pragma unroll
    for (int t = 0; t < 16; ++t) {
        int ppos = t * 64 + lane;
        u64 kw = __shfl(keep, t);
        float v = ((kw >> lane) & 1ull) ? 1.0f : 0.0f;
        keep_out[b * NPOS + order[b * NPOS + ppos]] = v;
    }
}

// ------------------------------------------------------------------------------
extern "C" void kernel_launch(void* const* d_in, const int* in_sizes, int n_in,
                              void* d_out, int out_size, void* d_ws, size_t ws_size,
                              hipStream_t stream)
{
    const float* feat = (const float*)d_in[0];
    const float* w    = (const float*)d_in[1];
    const float* bias = (const float*)d_in[2];

    float* out = (float*)d_out;
    float* boxes_out  = out;
    float* scores_out = out + NB * NPOS * 4;
    float* cls_out    = out + NB * NPOS * 5;
    float* keep_out   = out + NB * NPOS * 6;

    char* ws = (char*)d_ws;
    double* wpad  = (double*)(ws + OFF_W64);
    double* b64   = (double*)(ws + OFF_B64);
    int*    order = (int*)   (ws + OFF_ORDER);
    float4* sbox  = (float4*)(ws + OFF_SBOX);
    int*    scls  = (int*)   (ws + OFF_SCLS);
    u64*    validW= (u64*)   (ws + OFF_VALID);
    u64*    masksT= (u64*)   (ws + OFF_MASK);

    hipLaunchKernelGGL(k_cvt,  dim3(64),     dim3(256), 0, stream, w, bias, wpad, b64);
    hipLaunchKernelGGL(k_main, dim3(8, 64),  dim3(256), 0, stream, feat, wpad, b64,
                       boxes_out, scores_out, cls_out);
    hipLaunchKernelGGL(k_sort, dim3(64),     dim3(256), 0, stream, scores_out,
                       boxes_out, cls_out, order, sbox, scls, validW);
    hipLaunchKernelGGL(k_mask, dim3(64, 64), dim3(64),  0, stream, sbox, scls, masksT);
    hipLaunchKernelGGL(k_scan, dim3(64),     dim3(64),  0, stream, validW, masksT,
                       order, keep_out);
}